// Round 1
// baseline (759.460 us; speedup 1.0000x reference)
//
#include <hip/hip_runtime.h>
#include <math.h>

// ---------------- problem constants (fixed by setup_inputs) ----------------
constexpr int D   = 64;
constexpr int H   = 8;
constexpr int HD  = 8;
constexpr int NL  = 3;
constexpr int FFNx= 256;
constexpr int Bb  = 4;
constexpr int Ss  = 2048;
constexpr int NT  = Bb * Ss;        // 8192 tokens
constexpr int MAXC= 1024;
constexpr int MCL = 16;

// ---------------- workspace layout (float elements) ----------------
// total ~10.53M floats = ~42.1 MB
constexpr size_t WX  = 0;                        // [NT*D] hidden state
constexpr size_t WQ  = 2097152;                  // [NT*D]
constexpr size_t WK  = 4194304;                  // [NT*D]
constexpr size_t WV  = 6291456;                  // [NT*D]
constexpr size_t WO  = 8388608;                  // [NT*D]
constexpr size_t WU  = WQ;                       // [NT*FFN] aliases Q (dead then)
constexpr size_t WL1 = 10485760;                 // [NT] logit1 per token
constexpr size_t WEM = WL1 + NT;                 // [NT] end-mask (int)
constexpr size_t WCP = WEM + NT;                 // [NT] chunk*16+pos or -1 (int)
constexpr size_t WCT = WCP + NT;                 // [Ss*4] cos table
constexpr size_t WST = WCT + Ss*4;               // [Ss*4] sin table

// ---------------- init: copy x -> X, build rope tables ----------------
__global__ void k_init(const float* __restrict__ x, float* __restrict__ X,
                       float* __restrict__ ct, float* __restrict__ st) {
    int i = blockIdx.x * blockDim.x + threadIdx.x;
    constexpr int N4 = NT * D / 4;
    if (i < N4) ((float4*)X)[i] = ((const float4*)x)[i];
    if (i < Ss * 4) {
        int s = i >> 2, f = i & 3;
        // freqs are exactly 10^-f (10000^(f/4)); use literal table to match np
        const float fr[4] = {1.0f, 0.1f, 0.01f, 0.001f};
        float ang = (float)s * fr[f];
        ct[i] = cosf(ang);
        st[i] = sinf(ang);
    }
}

// ---------------- rmsnorm + QKV + rope (wave-per-token, weights in LDS) ----
__global__ __launch_bounds__(256) void k_qkv(
    const float* __restrict__ X, const float* __restrict__ Wq,
    const float* __restrict__ Wk, const float* __restrict__ Wv,
    const float* __restrict__ g1, const float* __restrict__ ct,
    const float* __restrict__ st, float* __restrict__ Q,
    float* __restrict__ K, float* __restrict__ V) {
    __shared__ float wq_s[D*D], wk_s[D*D], wv_s[D*D];
    __shared__ float g_s[D];
    __shared__ float hbuf[4][D];
    int tid = threadIdx.x;
    for (int i = tid; i < D*D; i += 256) {
        wq_s[i] = Wq[i]; wk_s[i] = Wk[i]; wv_s[i] = Wv[i];
    }
    if (tid < D) g_s[tid] = g1[tid];
    __syncthreads();
    int w = tid >> 6, d = tid & 63;
    int t0 = blockIdx.x * 32;
    for (int it = 0; it < 8; ++it) {
        int t = t0 + it*4 + w;
        float xv = X[t*D + d];
        float ss = xv * xv;
        #pragma unroll
        for (int off = 32; off; off >>= 1) ss += __shfl_xor(ss, off);
        float r = 1.0f / sqrtf(ss * (1.0f/D) + 1e-6f);
        float h = xv * g_s[d] * r;
        hbuf[w][d] = h;
        __syncthreads();
        float aq = 0.f, ak = 0.f, av = 0.f;
        #pragma unroll
        for (int j = 0; j < D; ++j) {
            float hj = hbuf[w][j];
            aq += hj * wq_s[j*D + d];
            ak += hj * wk_s[j*D + d];
            av += hj * wv_s[j*D + d];
        }
        // rope: dims within head: e<4 pairs with e+4 (lane xor 4, same head)
        int s  = t & (Ss - 1);
        int e  = d & 7;
        int fi = e & 3;
        float c  = ct[s*4 + fi];
        float sn = st[s*4 + fi];
        float pq = __shfl_xor(aq, 4);
        float pk = __shfl_xor(ak, 4);
        float rq, rk;
        if (e < 4) { rq = aq*c - pq*sn; rk = ak*c - pk*sn; }
        else       { rq = pq*sn + aq*c; rk = pk*sn + ak*c; }
        Q[t*D + d] = rq;
        K[t*D + d] = rk;
        V[t*D + d] = av;
        __syncthreads();
    }
}

// ---------------- causal flash attention, f32, HD=8 ----------------
// grid (S/64, B*H), block 256. Wave w handles queries w*16+(l&15); jpart=l>>4.
__global__ __launch_bounds__(256) void k_attn(
    const float* __restrict__ Q, const float* __restrict__ K,
    const float* __restrict__ V, float* __restrict__ O) {
    __shared__ float kl[64*9];
    __shared__ float vl[64*9];
    int qt = blockIdx.x;
    int bh = blockIdx.y;
    int b = bh >> 3, h = bh & 7;
    int tid = threadIdx.x;
    int w = tid >> 6, l = tid & 63;
    int iq = qt*64 + w*16 + (l & 15);
    int jp = l >> 4;
    const float* qp = Q + ((size_t)(b*Ss + iq))*D + h*HD;
    float q[8];
    #pragma unroll
    for (int e = 0; e < 8; ++e) q[e] = qp[e];
    float m = -INFINITY, lsum = 0.f;
    float o[8] = {0,0,0,0,0,0,0,0};
    int r = tid >> 2, c2 = (tid & 3) * 2;
    for (int kt = 0; kt <= qt; ++kt) {
        __syncthreads();
        const float* kp = K + ((size_t)(b*Ss + kt*64 + r))*D + h*HD + c2;
        const float* vp = V + ((size_t)(b*Ss + kt*64 + r))*D + h*HD + c2;
        float2 k2 = *(const float2*)kp;
        float2 v2 = *(const float2*)vp;
        kl[r*9 + c2] = k2.x; kl[r*9 + c2 + 1] = k2.y;
        vl[r*9 + c2] = v2.x; vl[r*9 + c2 + 1] = v2.y;
        __syncthreads();
        float sc[16];
        bool diag = (kt == qt);
        #pragma unroll
        for (int jj = 0; jj < 16; ++jj) {
            int j = jp*16 + jj;
            float s = 0.f;
            #pragma unroll
            for (int e = 0; e < 8; ++e) s += q[e] * kl[j*9 + e];
            s *= 0.35355339059327373f;   // 1/sqrt(8)
            if (diag && (kt*64 + j > iq)) s = -1e30f;
            sc[jj] = s;
        }
        float tm = sc[0];
        #pragma unroll
        for (int jj = 1; jj < 16; ++jj) tm = fmaxf(tm, sc[jj]);
        tm = fmaxf(tm, __shfl_xor(tm, 16));
        tm = fmaxf(tm, __shfl_xor(tm, 32));
        float mn = fmaxf(m, tm);
        float scale = expf(m - mn);
        m = mn;
        float ls = 0.f;
        float pv[16];
        #pragma unroll
        for (int jj = 0; jj < 16; ++jj) { pv[jj] = expf(sc[jj] - mn); ls += pv[jj]; }
        lsum = lsum * scale + ls;
        #pragma unroll
        for (int e = 0; e < 8; ++e) o[e] *= scale;
        #pragma unroll
        for (int jj = 0; jj < 16; ++jj) {
            int j = jp*16 + jj;
            #pragma unroll
            for (int e = 0; e < 8; ++e) o[e] += pv[jj] * vl[j*9 + e];
        }
    }
    #pragma unroll
    for (int e = 0; e < 8; ++e) {
        o[e] += __shfl_xor(o[e], 16);
        o[e] += __shfl_xor(o[e], 32);
    }
    lsum += __shfl_xor(lsum, 16);
    lsum += __shfl_xor(lsum, 32);
    float inv = 1.0f / lsum;
    float* op = O + ((size_t)(b*Ss + iq))*D + h*HD;
    op[jp*2]     = o[jp*2]     * inv;
    op[jp*2 + 1] = o[jp*2 + 1] * inv;
}

// ---------------- x += O @ Wo ----------------
__global__ __launch_bounds__(256) void k_post1(
    float* __restrict__ X, const float* __restrict__ Og,
    const float* __restrict__ Wo) {
    __shared__ float ws_[D*D];
    __shared__ float hbuf[4][D];
    int tid = threadIdx.x;
    for (int i = tid; i < D*D; i += 256) ws_[i] = Wo[i];
    __syncthreads();
    int w = tid >> 6, d = tid & 63;
    int t0 = blockIdx.x * 32;
    for (int it = 0; it < 8; ++it) {
        int t = t0 + it*4 + w;
        hbuf[w][d] = Og[t*D + d];
        __syncthreads();
        float a = 0.f;
        #pragma unroll
        for (int j = 0; j < D; ++j) a += hbuf[w][j] * ws_[j*D + d];
        X[t*D + d] += a;
        __syncthreads();
    }
}

// ---------------- rms2 + W1 + gelu -> U (16 tokens/block, f=thread) --------
__global__ __launch_bounds__(256) void k_ffn1(
    const float* __restrict__ X, const float* __restrict__ g2,
    const float* __restrict__ W1, float* __restrict__ U) {
    __shared__ float h2[16][D];
    __shared__ float part[16][16];
    __shared__ float g_s[D];
    int tid = threadIdx.x;
    if (tid < D) g_s[tid] = g2[tid];
    int t0 = blockIdx.x * 16;
    int tk = tid >> 4, li = tid & 15;
    float x0 = X[(t0+tk)*D + li];
    float x1 = X[(t0+tk)*D + li + 16];
    float x2 = X[(t0+tk)*D + li + 32];
    float x3 = X[(t0+tk)*D + li + 48];
    part[tk][li] = x0*x0 + x1*x1 + x2*x2 + x3*x3;
    __syncthreads();
    if (tid < 16) {
        float s = 0.f;
        #pragma unroll
        for (int i = 0; i < 16; ++i) s += part[tid][i];
        part[tid][0] = 1.0f / sqrtf(s * (1.0f/D) + 1e-6f);
    }
    __syncthreads();
    float r = part[tk][0];
    h2[tk][li]      = x0 * g_s[li]      * r;
    h2[tk][li + 16] = x1 * g_s[li + 16] * r;
    h2[tk][li + 32] = x2 * g_s[li + 32] * r;
    h2[tk][li + 48] = x3 * g_s[li + 48] * r;
    __syncthreads();
    int f = tid;
    float acc[16];
    #pragma unroll
    for (int i = 0; i < 16; ++i) acc[i] = 0.f;
    for (int j = 0; j < D; ++j) {
        float wv = W1[j*FFNx + f];
        #pragma unroll
        for (int i = 0; i < 16; ++i) acc[i] += h2[i][j] * wv;
    }
    #pragma unroll
    for (int i = 0; i < 16; ++i) {
        float u = acc[i];
        u = 0.5f * u * (1.0f + erff(u * 0.70710678118654752f));
        U[(t0 + i)*FFNx + f] = u;
    }
}

// ---------------- x += U @ W2 (16 tokens/block) ----------------
__global__ __launch_bounds__(256) void k_ffn2(
    float* __restrict__ X, const float* __restrict__ U,
    const float* __restrict__ W2) {
    __shared__ float ul[16][FFNx + 4];     // columns swizzled: cc = f + (f>>6)
    __shared__ float red[4][16][D];
    int tid = threadIdx.x;
    int t0 = blockIdx.x * 16;
    for (int i = tid; i < 16*FFNx; i += 256) {
        int tt = i >> 8, f = i & 255;
        ul[tt][f + (f >> 6)] = U[(t0 + tt)*FFNx + f];
    }
    __syncthreads();
    int d = tid & 63, fp = tid >> 6;
    float acc[16];
    #pragma unroll
    for (int i = 0; i < 16; ++i) acc[i] = 0.f;
    for (int fo = 0; fo < 64; ++fo) {
        int f = fp*64 + fo;
        float wv = W2[f*D + d];
        int cc = f + fp;
        #pragma unroll
        for (int i = 0; i < 16; ++i) acc[i] += ul[i][cc] * wv;
    }
    #pragma unroll
    for (int i = 0; i < 16; ++i) red[fp][i][d] = acc[i];
    __syncthreads();
    int tk = tid >> 6;
    #pragma unroll
    for (int k = 0; k < 4; ++k) {
        int tt = tk + k*4;
        float sum = red[0][tt][d] + red[1][tt][d] + red[2][tt][d] + red[3][tt][d];
        X[(t0 + tt)*D + d] += sum;
    }
}

// ---------------- head: logits, end-mask, logit1 ----------------
__global__ __launch_bounds__(256) void k_head(
    const float* __restrict__ X, const float* __restrict__ Wh,
    const float* __restrict__ bh, float* __restrict__ logit1,
    int* __restrict__ em) {
    int tid = threadIdx.x;
    int w = tid >> 6, d = tid & 63;
    int t = blockIdx.x*4 + w;
    float xv = X[t*D + d];
    float p0 = xv * Wh[d*2];
    float p1 = xv * Wh[d*2 + 1];
    #pragma unroll
    for (int off = 32; off; off >>= 1) {
        p0 += __shfl_xor(p0, off);
        p1 += __shfl_xor(p1, off);
    }
    if (d == 0) {
        float l0 = p0 + bh[0], l1 = p1 + bh[1];
        em[t] = (l0 > l1) ? 1 : 0;
        logit1[t] = l1;
    }
}

// ---------------- reg term: deterministic mean of logit1 ----------------
__global__ void k_reg(const float* __restrict__ logit1, float* __restrict__ outreg) {
    __shared__ float red[256];
    int tid = threadIdx.x;
    float s = 0.f;
    for (int i = tid; i < NT; i += 256) s += logit1[i];
    red[tid] = s;
    __syncthreads();
    for (int off = 128; off; off >>= 1) {
        if (tid < off) red[tid] += red[tid + off];
        __syncthreads();
    }
    if (tid == 0) *outreg = red[0] * (1.0f / NT);
}

// ---------------- per-batch scan: chunk_id / pos / valid ----------------
__global__ __launch_bounds__(256) void k_scan(const int* __restrict__ em,
                                              int* __restrict__ cp) {
    __shared__ int ssum[256], smax[256];
    __shared__ int sany, stot;
    int b = blockIdx.x, tid = threadIdx.x;
    const int* e = em + b*Ss;
    int base = tid * 8;
    int loc[8];
    int lsum = 0, lor = 0;
    #pragma unroll
    for (int i = 0; i < 8; ++i) { loc[i] = e[base + i]; lsum += loc[i]; lor |= loc[i]; }
    ssum[tid] = lor;
    __syncthreads();
    if (tid == 0) { int a = 0; for (int i = 0; i < 256; ++i) a |= ssum[i]; sany = a; }
    __syncthreads();
    int any = sany;
    __syncthreads();
    if (!any && tid == 255) { loc[7] = 1; lsum = 1; }
    // start markers: mk[s] = (prev is end || s==0) ? s : -1
    int prev = (tid == 0) ? 1 : e[base - 1];
    if (!any && tid) prev = 0;  // when no ends, raw em is all zero anyway
    int mk[8];
    int lmax = -1;
    #pragma unroll
    for (int i = 0; i < 8; ++i) {
        int pe = (i == 0) ? prev : loc[i - 1];
        // note: loc[7] modification only affects position 2048 (nonexistent)
        if (i == 7 && !any && tid == 255) pe = e[base + 6];  // raw value
        mk[i] = pe ? (base + i) : -1;
        lmax = max(lmax, mk[i]);
    }
    ssum[tid] = lsum; smax[tid] = lmax;
    __syncthreads();
    if (tid == 0) {
        int rs = 0, rm = -1;
        for (int i = 0; i < 256; ++i) {
            int ts = ssum[i], tm = smax[i];
            ssum[i] = rs; smax[i] = rm;
            rs += ts; rm = max(rm, tm);
        }
        stot = rs;
    }
    __syncthreads();
    int run = ssum[tid], rmax = smax[tid], tot = stot;
    int* cpb = cp + b*Ss;
    #pragma unroll
    for (int i = 0; i < 8; ++i) {
        int s = base + i;
        rmax = max(rmax, mk[i]);
        int chunk = run;          // exclusive cumsum == cumsum - em
        run += loc[i];
        int pos = s - rmax;
        bool valid = (chunk < tot) && (chunk < MAXC) && (pos < MCL);
        cpb[s] = valid ? (chunk * MCL + pos) : -1;
    }
}

// ---------------- fill out with pad vector / pad ids ----------------
__global__ void k_fill(float* __restrict__ out, const float* __restrict__ pad,
                       const int* __restrict__ padid) {
    int i = blockIdx.x * blockDim.x + threadIdx.x;
    constexpr int N4  = Bb * MAXC * MCL * D / 4;   // 1048576
    constexpr int NI4 = Bb * MAXC * MCL / 4;       // 16384
    if (i < N4) {
        ((float4*)out)[i] = ((const float4*)pad)[i & 15];
    } else if (i < N4 + NI4) {
        float pv = (float)(*padid);
        float4 v; v.x = pv; v.y = pv; v.z = pv; v.w = pv;
        ((float4*)out)[i] = v;
    }
}

// ---------------- scatter valid tokens ----------------
__global__ __launch_bounds__(256) void k_scatter(
    const float* __restrict__ X, const int* __restrict__ cp,
    const int* __restrict__ ids, float* __restrict__ out) {
    int tid = threadIdx.x;
    int w = tid >> 6, d = tid & 63;
    int t = blockIdx.x*4 + w;
    int c = cp[t];
    if (c < 0) return;
    int b = t >> 11;
    float* dst = out + ((size_t)(b * MAXC * MCL) + c) * D;
    dst[d] = X[t*D + d];
    if (d == 0)
        out[(size_t)Bb*MAXC*MCL*D + (size_t)b*MAXC*MCL + c] = (float)ids[t];
}

// ---------------- launch ----------------
extern "C" void kernel_launch(void* const* d_in, const int* in_sizes, int n_in,
                              void* d_out, int out_size, void* d_ws, size_t ws_size,
                              hipStream_t stream) {
    const float* x    = (const float*)d_in[0];
    const float* pad  = (const float*)d_in[1];
    const int*   xids = (const int*)  d_in[2];
    const int*   padid= (const int*)  d_in[3];
    const float* Wq   = (const float*)d_in[4];
    const float* Wk   = (const float*)d_in[5];
    const float* Wv   = (const float*)d_in[6];
    const float* Wo   = (const float*)d_in[7];
    const float* ln1  = (const float*)d_in[8];
    const float* ln2  = (const float*)d_in[9];
    const float* W1   = (const float*)d_in[10];
    const float* W2   = (const float*)d_in[11];
    const float* Wh   = (const float*)d_in[12];
    const float* bh   = (const float*)d_in[13];
    float* out = (float*)d_out;
    float* ws  = (float*)d_ws;

    float* X  = ws + WX;
    float* Qb = ws + WQ;
    float* Kb = ws + WK;
    float* Vb = ws + WV;
    float* Ob = ws + WO;
    float* Ub = ws + WU;
    float* L1b= ws + WL1;
    int*   EMb= (int*)(ws + WEM);
    int*   CPb= (int*)(ws + WCP);
    float* ct = ws + WCT;
    float* st = ws + WST;

    k_init<<<2048, 256, 0, stream>>>(x, X, ct, st);
    for (int l = 0; l < NL; ++l) {
        k_qkv <<<256, 256, 0, stream>>>(X, Wq + l*D*D, Wk + l*D*D, Wv + l*D*D,
                                        ln1 + l*D, ct, st, Qb, Kb, Vb);
        k_attn<<<dim3(Ss/64, Bb*H), 256, 0, stream>>>(Qb, Kb, Vb, Ob);
        k_post1<<<256, 256, 0, stream>>>(X, Ob, Wo + l*D*D);
        k_ffn1<<<NT/16, 256, 0, stream>>>(X, ln2 + l*D, W1 + l*D*FFNx, Ub);
        k_ffn2<<<NT/16, 256, 0, stream>>>(X, Ub, W2 + l*FFNx*D);
    }
    k_head<<<NT/4, 256, 0, stream>>>(X, Wh, bh, L1b, EMb);
    k_reg <<<1, 256, 0, stream>>>(L1b, out + (size_t)Bb*MAXC*MCL*D + Bb*MAXC*MCL);
    k_scan<<<Bb, 256, 0, stream>>>(EMb, CPb);
    k_fill<<<(Bb*MAXC*MCL*D/4 + Bb*MAXC*MCL/4 + 255)/256, 256, 0, stream>>>(out, pad, padid);
    k_scatter<<<NT/4, 256, 0, stream>>>(X, CPb, xids, out);
}

// Round 2
// 622.892 us; speedup vs baseline: 1.2192x; 1.2192x over previous
//
#include <hip/hip_runtime.h>
#include <math.h>

// ---------------- problem constants (fixed by setup_inputs) ----------------
constexpr int D   = 64;
constexpr int H   = 8;
constexpr int HD  = 8;
constexpr int NL  = 3;
constexpr int FFNx= 256;
constexpr int Bb  = 4;
constexpr int Ss  = 2048;
constexpr int NT  = Bb * Ss;        // 8192 tokens
constexpr int MAXC= 1024;
constexpr int MCL = 16;

// attention task decomposition
constexpr int QW   = 128;            // queries per wave (2 per lane)
constexpr int CH   = 256;            // keys per chunk task
constexpr int TPB  = 72;             // tasks per (b,h) = sum_t ceil((t+1)/2), t=0..15
constexpr int NTASK= 32 * TPB;       // 2304 waves

// ---------------- workspace layout (float elements) ----------------
constexpr size_t WX  = 0;                        // [NT*D]
constexpr size_t WQ  = 2097152;                  // [NT*D]   (aliased by U later)
constexpr size_t WKV = 4194304;                  // [32*2048*16] interleaved K|V
constexpr size_t WO  = 5242880;                  // [NT*D]
constexpr size_t WPB = 7340032;                  // [NTASK*1280] attn partials
constexpr size_t WU  = WQ;                       // [NT*FFN] aliases Q
constexpr size_t WL1 = 10289152;                 // [NT]
constexpr size_t WEM = WL1 + NT;                 // [NT] int
constexpr size_t WCP = WEM + NT;                 // [NT] int
constexpr size_t WCT = WCP + NT;                 // [Ss*4]
constexpr size_t WST = WCT + Ss*4;               // [Ss*4]

// ---------------- init: copy x -> X, build rope tables ----------------
__global__ void k_init(const float* __restrict__ x, float* __restrict__ X,
                       float* __restrict__ ct, float* __restrict__ st) {
    int i = blockIdx.x * blockDim.x + threadIdx.x;
    constexpr int N4 = NT * D / 4;
    if (i < N4) ((float4*)X)[i] = ((const float4*)x)[i];
    if (i < Ss * 4) {
        int s = i >> 2, f = i & 3;
        const float fr[4] = {1.0f, 0.1f, 0.01f, 0.001f};
        float ang = (float)s * fr[f];
        ct[i] = cosf(ang);
        st[i] = sinf(ang);
    }
}

// ---------------- rmsnorm + QKV + rope (wave-per-token, weights in LDS) ----
// Q -> [b,s,h*8+e]; K,V -> interleaved KV[bh][s][0..7=K, 8..15=V]
__global__ __launch_bounds__(256) void k_qkv(
    const float* __restrict__ X, const float* __restrict__ Wq,
    const float* __restrict__ Wk, const float* __restrict__ Wv,
    const float* __restrict__ g1, const float* __restrict__ ct,
    const float* __restrict__ st, float* __restrict__ Q,
    float* __restrict__ KV) {
    __shared__ float wq_s[D*D], wk_s[D*D], wv_s[D*D];
    __shared__ float g_s[D];
    __shared__ float hbuf[4][D];
    int tid = threadIdx.x;
    for (int i = tid; i < D*D; i += 256) {
        wq_s[i] = Wq[i]; wk_s[i] = Wk[i]; wv_s[i] = Wv[i];
    }
    if (tid < D) g_s[tid] = g1[tid];
    __syncthreads();
    int w = tid >> 6, d = tid & 63;
    int t0 = blockIdx.x * 32;
    for (int it = 0; it < 8; ++it) {
        int t = t0 + it*4 + w;
        float xv = X[t*D + d];
        float ss = xv * xv;
        #pragma unroll
        for (int off = 32; off; off >>= 1) ss += __shfl_xor(ss, off);
        float r = 1.0f / sqrtf(ss * (1.0f/D) + 1e-6f);
        float h = xv * g_s[d] * r;
        hbuf[w][d] = h;
        __syncthreads();
        float aq = 0.f, ak = 0.f, av = 0.f;
        #pragma unroll
        for (int j = 0; j < D; ++j) {
            float hj = hbuf[w][j];
            aq += hj * wq_s[j*D + d];
            ak += hj * wk_s[j*D + d];
            av += hj * wv_s[j*D + d];
        }
        int s  = t & (Ss - 1);
        int e  = d & 7;
        int fi = e & 3;
        float c  = ct[s*4 + fi];
        float sn = st[s*4 + fi];
        float pq = __shfl_xor(aq, 4);
        float pk = __shfl_xor(ak, 4);
        float rq, rk;
        if (e < 4) { rq = aq*c - pq*sn; rk = ak*c - pk*sn; }
        else       { rq = pq*sn + aq*c; rk = pk*sn + ak*c; }
        Q[t*D + d] = rq;
        int bq = t >> 11;
        int hh = d >> 3;
        float* kvp = KV + ((((size_t)(bq*H + hh))*Ss + s) << 4);
        kvp[e]     = rk;
        kvp[8 + e] = av;
        __syncthreads();
    }
}

// ---------------- causal attention, split-K, no LDS ----------------
// wave = one task (bh, qwave t, chunk s). 2 queries/lane, uniform KV loads.
__global__ __launch_bounds__(256) void k_attn2(
    const float* __restrict__ Qg, const float* __restrict__ KV,
    float* __restrict__ PB) {
    int wid = (blockIdx.x << 2) + (threadIdx.x >> 6);
    int L = threadIdx.x & 63;
    int bh = wid / TPB;
    int rem = wid - bh * TPB;
    int t = 0, nc = 1;
    while (rem >= nc) { rem -= nc; ++t; nc = (t + 2) >> 1; }
    int s = rem;
    int b = bh >> 3, h = bh & 7;
    int qmin = t * QW;
    int k0 = s * CH;
    int kend = min(k0 + CH, qmin + QW);
    int nkey = kend - k0;

    const float sc8 = 0.35355339059327373f;   // 1/sqrt(8)
    const float* qp = Qg + ((size_t)(b*Ss + qmin + L))*D + h*HD;
    float4 qa0 = *(const float4*)(qp);
    float4 qb0 = *(const float4*)(qp + 4);
    float4 qa1 = *(const float4*)(qp + 64*D);
    float4 qb1 = *(const float4*)(qp + 64*D + 4);
    qa0.x*=sc8; qa0.y*=sc8; qa0.z*=sc8; qa0.w*=sc8;
    qb0.x*=sc8; qb0.y*=sc8; qb0.z*=sc8; qb0.w*=sc8;
    qa1.x*=sc8; qa1.y*=sc8; qa1.z*=sc8; qa1.w*=sc8;
    qb1.x*=sc8; qb1.y*=sc8; qb1.z*=sc8; qb1.w*=sc8;

    float m0 = -INFINITY, m1 = -INFINITY, l0 = 0.f, l1 = 0.f;
    float o0[8] = {0,0,0,0,0,0,0,0};
    float o1[8] = {0,0,0,0,0,0,0,0};

    const float4* kvb = (const float4*)(KV + (((size_t)bh*Ss + k0) << 4));

    for (int j0 = 0; j0 < nkey; j0 += 16) {
        float s0[16], s1[16];
        #pragma unroll
        for (int jj = 0; jj < 16; ++jj) {
            const float4* kv = kvb + (size_t)(j0 + jj)*4;
            float4 ka = kv[0];
            float4 kb = kv[1];
            s0[jj] = qa0.x*ka.x + qa0.y*ka.y + qa0.z*ka.z + qa0.w*ka.w
                   + qb0.x*kb.x + qb0.y*kb.y + qb0.z*kb.z + qb0.w*kb.w;
            s1[jj] = qa1.x*ka.x + qa1.y*ka.y + qa1.z*ka.z + qa1.w*ka.w
                   + qb1.x*kb.x + qb1.y*kb.y + qb1.z*kb.z + qb1.w*kb.w;
        }
        int relbase = k0 + j0 - qmin;
        if (relbase + 15 > 0) {          // wave-uniform: mask only near diagonal
            #pragma unroll
            for (int jj = 0; jj < 16; ++jj) {
                int rel = relbase + jj;
                if (rel > L)      s0[jj] = -1e30f;
                if (rel > L + 64) s1[jj] = -1e30f;
            }
        }
        float tm0 = s0[0], tm1 = s1[0];
        #pragma unroll
        for (int jj = 1; jj < 16; ++jj) {
            tm0 = fmaxf(tm0, s0[jj]);
            tm1 = fmaxf(tm1, s1[jj]);
        }
        float mn0 = fmaxf(m0, tm0), mn1 = fmaxf(m1, tm1);
        float r0 = expf(m0 - mn0), r1 = expf(m1 - mn1);
        m0 = mn0; m1 = mn1;
        l0 *= r0; l1 *= r1;
        #pragma unroll
        for (int e = 0; e < 8; ++e) { o0[e] *= r0; o1[e] *= r1; }
        #pragma unroll
        for (int jj = 0; jj < 16; ++jj) {
            const float4* kv = kvb + (size_t)(j0 + jj)*4;
            float4 va = kv[2];
            float4 vb = kv[3];
            float p0 = expf(s0[jj] - mn0);
            float p1 = expf(s1[jj] - mn1);
            l0 += p0; l1 += p1;
            o0[0] += p0*va.x; o0[1] += p0*va.y; o0[2] += p0*va.z; o0[3] += p0*va.w;
            o0[4] += p0*vb.x; o0[5] += p0*vb.y; o0[6] += p0*vb.z; o0[7] += p0*vb.w;
            o1[0] += p1*va.x; o1[1] += p1*va.y; o1[2] += p1*va.z; o1[3] += p1*va.w;
            o1[4] += p1*vb.x; o1[5] += p1*vb.y; o1[6] += p1*vb.z; o1[7] += p1*vb.w;
        }
    }
    float* pb = PB + (size_t)wid * 1280;
    pb[L]        = m0; pb[64 + L]        = m1;
    pb[128 + L]  = l0; pb[128 + 64 + L]  = l1;
    #pragma unroll
    for (int e = 0; e < 8; ++e) {
        pb[(2+e)*128 + L]      = o0[e];
        pb[(2+e)*128 + 64 + L] = o1[e];
    }
}

// ---------------- combine partials -> O ----------------
__global__ __launch_bounds__(128) void k_comb(const float* __restrict__ PB,
                                              float* __restrict__ Og) {
    int qs = threadIdx.x;           // 0..127
    int t  = blockIdx.x & 15;
    int bh = blockIdx.x >> 4;
    int b = bh >> 3, h = bh & 7;
    int nc = (t + 2) >> 1;
    int base = 0;
    for (int u = 0; u < t; ++u) base += (u + 2) >> 1;
    const float* pb0 = PB + (size_t)(bh*TPB + base) * 1280;
    float M = -INFINITY, Lx = 0.f;
    float O[8] = {0,0,0,0,0,0,0,0};
    for (int s3 = 0; s3 < nc; ++s3) {
        const float* pb = pb0 + (size_t)s3 * 1280;
        float m = pb[qs];
        float l = pb[128 + qs];
        float nm = fmaxf(M, m);
        float a = expf(M - nm), c = expf(m - nm);
        Lx = Lx*a + l*c;
        #pragma unroll
        for (int e = 0; e < 8; ++e) O[e] = O[e]*a + pb[(2+e)*128 + qs]*c;
        M = nm;
    }
    float inv = 1.0f / Lx;
    float* op = Og + ((size_t)(b*Ss + t*QW + qs))*D + h*HD;
    #pragma unroll
    for (int e = 0; e < 8; ++e) op[e] = O[e] * inv;
}

// ---------------- x += O @ Wo ----------------
__global__ __launch_bounds__(256) void k_post1(
    float* __restrict__ X, const float* __restrict__ Og,
    const float* __restrict__ Wo) {
    __shared__ float ws_[D*D];
    __shared__ float hbuf[4][D];
    int tid = threadIdx.x;
    for (int i = tid; i < D*D; i += 256) ws_[i] = Wo[i];
    __syncthreads();
    int w = tid >> 6, d = tid & 63;
    int t0 = blockIdx.x * 32;
    for (int it = 0; it < 8; ++it) {
        int t = t0 + it*4 + w;
        hbuf[w][d] = Og[t*D + d];
        __syncthreads();
        float a = 0.f;
        #pragma unroll
        for (int j = 0; j < D; ++j) a += hbuf[w][j] * ws_[j*D + d];
        X[t*D + d] += a;
        __syncthreads();
    }
}

// ---------------- rms2 + W1 + gelu -> U ----------------
__global__ __launch_bounds__(256) void k_ffn1(
    const float* __restrict__ X, const float* __restrict__ g2,
    const float* __restrict__ W1, float* __restrict__ U) {
    __shared__ float h2[16][D];
    __shared__ float part[16][16];
    __shared__ float g_s[D];
    int tid = threadIdx.x;
    if (tid < D) g_s[tid] = g2[tid];
    int t0 = blockIdx.x * 16;
    int tk = tid >> 4, li = tid & 15;
    float x0 = X[(t0+tk)*D + li];
    float x1 = X[(t0+tk)*D + li + 16];
    float x2 = X[(t0+tk)*D + li + 32];
    float x3 = X[(t0+tk)*D + li + 48];
    part[tk][li] = x0*x0 + x1*x1 + x2*x2 + x3*x3;
    __syncthreads();
    if (tid < 16) {
        float s = 0.f;
        #pragma unroll
        for (int i = 0; i < 16; ++i) s += part[tid][i];
        part[tid][0] = 1.0f / sqrtf(s * (1.0f/D) + 1e-6f);
    }
    __syncthreads();
    float r = part[tk][0];
    h2[tk][li]      = x0 * g_s[li]      * r;
    h2[tk][li + 16] = x1 * g_s[li + 16] * r;
    h2[tk][li + 32] = x2 * g_s[li + 32] * r;
    h2[tk][li + 48] = x3 * g_s[li + 48] * r;
    __syncthreads();
    int f = tid;
    float acc[16];
    #pragma unroll
    for (int i = 0; i < 16; ++i) acc[i] = 0.f;
    for (int j = 0; j < D; ++j) {
        float wv = W1[j*FFNx + f];
        #pragma unroll
        for (int i = 0; i < 16; ++i) acc[i] += h2[i][j] * wv;
    }
    #pragma unroll
    for (int i = 0; i < 16; ++i) {
        float u = acc[i];
        u = 0.5f * u * (1.0f + erff(u * 0.70710678118654752f));
        U[(t0 + i)*FFNx + f] = u;
    }
}

// ---------------- x += U @ W2 ----------------
__global__ __launch_bounds__(256) void k_ffn2(
    float* __restrict__ X, const float* __restrict__ U,
    const float* __restrict__ W2) {
    __shared__ float ul[16][FFNx + 4];
    __shared__ float red[4][16][D];
    int tid = threadIdx.x;
    int t0 = blockIdx.x * 16;
    for (int i = tid; i < 16*FFNx; i += 256) {
        int tt = i >> 8, f = i & 255;
        ul[tt][f + (f >> 6)] = U[(t0 + tt)*FFNx + f];
    }
    __syncthreads();
    int d = tid & 63, fp = tid >> 6;
    float acc[16];
    #pragma unroll
    for (int i = 0; i < 16; ++i) acc[i] = 0.f;
    for (int fo = 0; fo < 64; ++fo) {
        int f = fp*64 + fo;
        float wv = W2[f*D + d];
        int cc = f + fp;
        #pragma unroll
        for (int i = 0; i < 16; ++i) acc[i] += ul[i][cc] * wv;
    }
    #pragma unroll
    for (int i = 0; i < 16; ++i) red[fp][i][d] = acc[i];
    __syncthreads();
    int tk = tid >> 6;
    #pragma unroll
    for (int k = 0; k < 4; ++k) {
        int tt = tk + k*4;
        float sum = red[0][tt][d] + red[1][tt][d] + red[2][tt][d] + red[3][tt][d];
        X[(t0 + tt)*D + d] += sum;
    }
}

// ---------------- head ----------------
__global__ __launch_bounds__(256) void k_head(
    const float* __restrict__ X, const float* __restrict__ Wh,
    const float* __restrict__ bh, float* __restrict__ logit1,
    int* __restrict__ em) {
    int tid = threadIdx.x;
    int w = tid >> 6, d = tid & 63;
    int t = blockIdx.x*4 + w;
    float xv = X[t*D + d];
    float p0 = xv * Wh[d*2];
    float p1 = xv * Wh[d*2 + 1];
    #pragma unroll
    for (int off = 32; off; off >>= 1) {
        p0 += __shfl_xor(p0, off);
        p1 += __shfl_xor(p1, off);
    }
    if (d == 0) {
        float l0 = p0 + bh[0], l1 = p1 + bh[1];
        em[t] = (l0 > l1) ? 1 : 0;
        logit1[t] = l1;
    }
}

// ---------------- reg term ----------------
__global__ void k_reg(const float* __restrict__ logit1, float* __restrict__ outreg) {
    __shared__ float red[256];
    int tid = threadIdx.x;
    float s = 0.f;
    for (int i = tid; i < NT; i += 256) s += logit1[i];
    red[tid] = s;
    __syncthreads();
    for (int off = 128; off; off >>= 1) {
        if (tid < off) red[tid] += red[tid + off];
        __syncthreads();
    }
    if (tid == 0) *outreg = red[0] * (1.0f / NT);
}

// ---------------- per-batch scan ----------------
__global__ __launch_bounds__(256) void k_scan(const int* __restrict__ em,
                                              int* __restrict__ cp) {
    __shared__ int ssum[256], smax[256];
    __shared__ int sany, stot;
    int b = blockIdx.x, tid = threadIdx.x;
    const int* e = em + b*Ss;
    int base = tid * 8;
    int loc[8];
    int lsum = 0, lor = 0;
    #pragma unroll
    for (int i = 0; i < 8; ++i) { loc[i] = e[base + i]; lsum += loc[i]; lor |= loc[i]; }
    ssum[tid] = lor;
    __syncthreads();
    if (tid == 0) { int a = 0; for (int i = 0; i < 256; ++i) a |= ssum[i]; sany = a; }
    __syncthreads();
    int any = sany;
    __syncthreads();
    if (!any && tid == 255) { loc[7] = 1; lsum = 1; }
    int prev = (tid == 0) ? 1 : e[base - 1];
    if (!any && tid) prev = 0;
    int mk[8];
    int lmax = -1;
    #pragma unroll
    for (int i = 0; i < 8; ++i) {
        int pe = (i == 0) ? prev : loc[i - 1];
        if (i == 7 && !any && tid == 255) pe = e[base + 6];
        mk[i] = pe ? (base + i) : -1;
        lmax = max(lmax, mk[i]);
    }
    ssum[tid] = lsum; smax[tid] = lmax;
    __syncthreads();
    if (tid == 0) {
        int rs = 0, rm = -1;
        for (int i = 0; i < 256; ++i) {
            int ts = ssum[i], tm = smax[i];
            ssum[i] = rs; smax[i] = rm;
            rs += ts; rm = max(rm, tm);
        }
        stot = rs;
    }
    __syncthreads();
    int run = ssum[tid], rmax = smax[tid], tot = stot;
    int* cpb = cp + b*Ss;
    #pragma unroll
    for (int i = 0; i < 8; ++i) {
        int s = base + i;
        rmax = max(rmax, mk[i]);
        int chunk = run;
        run += loc[i];
        int pos = s - rmax;
        bool valid = (chunk < tot) && (chunk < MAXC) && (pos < MCL);
        cpb[s] = valid ? (chunk * MCL + pos) : -1;
    }
}

// ---------------- fill / scatter ----------------
__global__ void k_fill(float* __restrict__ out, const float* __restrict__ pad,
                       const int* __restrict__ padid) {
    int i = blockIdx.x * blockDim.x + threadIdx.x;
    constexpr int N4  = Bb * MAXC * MCL * D / 4;
    constexpr int NI4 = Bb * MAXC * MCL / 4;
    if (i < N4) {
        ((float4*)out)[i] = ((const float4*)pad)[i & 15];
    } else if (i < N4 + NI4) {
        float pv = (float)(*padid);
        float4 v; v.x = pv; v.y = pv; v.z = pv; v.w = pv;
        ((float4*)out)[i] = v;
    }
}

__global__ __launch_bounds__(256) void k_scatter(
    const float* __restrict__ X, const int* __restrict__ cp,
    const int* __restrict__ ids, float* __restrict__ out) {
    int tid = threadIdx.x;
    int w = tid >> 6, d = tid & 63;
    int t = blockIdx.x*4 + w;
    int c = cp[t];
    if (c < 0) return;
    int b = t >> 11;
    float* dst = out + ((size_t)(b * MAXC * MCL) + c) * D;
    dst[d] = X[t*D + d];
    if (d == 0)
        out[(size_t)Bb*MAXC*MCL*D + (size_t)b*MAXC*MCL + c] = (float)ids[t];
}

// ---------------- launch ----------------
extern "C" void kernel_launch(void* const* d_in, const int* in_sizes, int n_in,
                              void* d_out, int out_size, void* d_ws, size_t ws_size,
                              hipStream_t stream) {
    const float* x    = (const float*)d_in[0];
    const float* pad  = (const float*)d_in[1];
    const int*   xids = (const int*)  d_in[2];
    const int*   padid= (const int*)  d_in[3];
    const float* Wq   = (const float*)d_in[4];
    const float* Wk   = (const float*)d_in[5];
    const float* Wv   = (const float*)d_in[6];
    const float* Wo   = (const float*)d_in[7];
    const float* ln1  = (const float*)d_in[8];
    const float* ln2  = (const float*)d_in[9];
    const float* W1   = (const float*)d_in[10];
    const float* W2   = (const float*)d_in[11];
    const float* Wh   = (const float*)d_in[12];
    const float* bh   = (const float*)d_in[13];
    float* out = (float*)d_out;
    float* ws  = (float*)d_ws;

    float* X  = ws + WX;
    float* Qb = ws + WQ;
    float* KVb= ws + WKV;
    float* Ob = ws + WO;
    float* PBb= ws + WPB;
    float* Ub = ws + WU;
    float* L1b= ws + WL1;
    int*   EMb= (int*)(ws + WEM);
    int*   CPb= (int*)(ws + WCP);
    float* ct = ws + WCT;
    float* st = ws + WST;

    k_init<<<2048, 256, 0, stream>>>(x, X, ct, st);
    for (int l = 0; l < NL; ++l) {
        k_qkv <<<256, 256, 0, stream>>>(X, Wq + l*D*D, Wk + l*D*D, Wv + l*D*D,
                                        ln1 + l*D, ct, st, Qb, KVb);
        k_attn2<<<NTASK/4, 256, 0, stream>>>(Qb, KVb, PBb);
        k_comb <<<32*16, 128, 0, stream>>>(PBb, Ob);
        k_post1<<<256, 256, 0, stream>>>(X, Ob, Wo + l*D*D);
        k_ffn1<<<NT/16, 256, 0, stream>>>(X, ln2 + l*D, W1 + l*D*FFNx, Ub);
        k_ffn2<<<NT/16, 256, 0, stream>>>(X, Ub, W2 + l*FFNx*D);
    }
    k_head<<<NT/4, 256, 0, stream>>>(X, Wh, bh, L1b, EMb);
    k_reg <<<1, 256, 0, stream>>>(L1b, out + (size_t)Bb*MAXC*MCL*D + Bb*MAXC*MCL);
    k_scan<<<Bb, 256, 0, stream>>>(EMb, CPb);
    k_fill<<<(Bb*MAXC*MCL*D/4 + Bb*MAXC*MCL/4 + 255)/256, 256, 0, stream>>>(out, pad, padid);
    k_scatter<<<NT/4, 256, 0, stream>>>(X, CPb, xids, out);
}

// Round 3
// 487.040 us; speedup vs baseline: 1.5593x; 1.2789x over previous
//
#include <hip/hip_runtime.h>
#include <math.h>

// ---------------- problem constants (fixed by setup_inputs) ----------------
constexpr int D   = 64;
constexpr int H   = 8;
constexpr int HD  = 8;
constexpr int NL  = 3;
constexpr int FFNx= 256;
constexpr int Bb  = 4;
constexpr int Ss  = 2048;
constexpr int NT  = Bb * Ss;        // 8192 tokens
constexpr int MAXC= 1024;
constexpr int MCL = 16;

// attention task decomposition (chunk-major enumeration for L1 sharing)
constexpr int QW   = 128;            // queries per wave (2 per lane)
constexpr int CH   = 256;            // keys per chunk task
constexpr int TPB  = 72;             // tasks per (b,h): sum_s (16-2s), s=0..7
constexpr int NTASK= 32 * TPB;       // 2304 waves

// ---------------- workspace layout (float elements) ----------------
constexpr size_t WX  = 0;                        // [NT*D]
constexpr size_t WQ  = 2097152;                  // [NT*D]   (aliased by U later)
constexpr size_t WKV = 4194304;                  // [32*2048*16] interleaved K|V
constexpr size_t WO  = 5242880;                  // [NT*D]
constexpr size_t WPB = 7340032;                  // [NTASK*1280] attn partials
constexpr size_t WU  = WQ;                       // [NT*FFN] aliases Q
constexpr size_t WL1 = 10289152;                 // [NT]
constexpr size_t WEM = WL1 + NT;                 // [NT] int
constexpr size_t WCP = WEM + NT;                 // [NT] int
constexpr size_t WCT = WCP + NT;                 // [Ss*4]
constexpr size_t WST = WCT + Ss*4;               // [Ss*4]

constexpr float LOG2E = 1.4426950408889634f;

__device__ __forceinline__ float rdlane(float v, int l) {
    return __builtin_bit_cast(float, __builtin_amdgcn_readlane(__builtin_bit_cast(int, v), l));
}

// ---------------- init: copy x -> X, build rope tables ----------------
__global__ void k_init(const float* __restrict__ x, float* __restrict__ X,
                       float* __restrict__ ct, float* __restrict__ st) {
    int i = blockIdx.x * blockDim.x + threadIdx.x;
    constexpr int N4 = NT * D / 4;
    if (i < N4) ((float4*)X)[i] = ((const float4*)x)[i];
    if (i < Ss * 4) {
        int s = i >> 2, f = i & 3;
        const float fr[4] = {1.0f, 0.1f, 0.01f, 0.001f};
        float ang = (float)s * fr[f];
        ct[i] = cosf(ang);
        st[i] = sinf(ang);
    }
}

// ---------------- rmsnorm + QKV + rope (wave-per-token, readlane bcast) ----
// Q -> [b,s,h*8+e]; K,V -> interleaved KV[bh][s][0..7=K, 8..15=V]
__global__ __launch_bounds__(256) void k_qkv(
    const float* __restrict__ X, const float* __restrict__ Wq,
    const float* __restrict__ Wk, const float* __restrict__ Wv,
    const float* __restrict__ g1, const float* __restrict__ ct,
    const float* __restrict__ st, float* __restrict__ Q,
    float* __restrict__ KV) {
    __shared__ float wq_s[D*D], wk_s[D*D], wv_s[D*D];
    __shared__ float g_s[D];
    int tid = threadIdx.x;
    for (int i = tid; i < D*D; i += 256) {
        wq_s[i] = Wq[i]; wk_s[i] = Wk[i]; wv_s[i] = Wv[i];
    }
    if (tid < D) g_s[tid] = g1[tid];
    __syncthreads();
    int w = tid >> 6, d = tid & 63;
    int t0 = blockIdx.x * 32;
    for (int it = 0; it < 8; ++it) {
        int t = t0 + it*4 + w;
        float xv = X[t*D + d];
        float ss = xv * xv;
        #pragma unroll
        for (int off = 32; off; off >>= 1) ss += __shfl_xor(ss, off);
        float r = 1.0f / sqrtf(ss * (1.0f/D) + 1e-6f);
        float h = xv * g_s[d] * r;
        float aq = 0.f, ak = 0.f, av = 0.f;
        #pragma unroll
        for (int j = 0; j < D; ++j) {
            float hj = rdlane(h, j);
            aq += hj * wq_s[j*D + d];
            ak += hj * wk_s[j*D + d];
            av += hj * wv_s[j*D + d];
        }
        int s  = t & (Ss - 1);
        int e  = d & 7;
        int fi = e & 3;
        float c  = ct[s*4 + fi];
        float sn = st[s*4 + fi];
        float pq = __shfl_xor(aq, 4);
        float pk = __shfl_xor(ak, 4);
        float rq, rk;
        if (e < 4) { rq = aq*c - pq*sn; rk = ak*c - pk*sn; }
        else       { rq = pq*sn + aq*c; rk = pk*sn + ak*c; }
        Q[t*D + d] = rq;
        int bq = t >> 11;
        int hh = d >> 3;
        float* kvp = KV + ((((size_t)(bq*H + hh))*Ss + s) << 4);
        kvp[e]     = rk;
        kvp[8 + e] = av;
    }
}

// ---------------- causal attention, split-K, exp2 domain, no LDS ----------
// task enumeration chunk-major: s outer (off(s)=s*(17-s)), t=2s..15 inner.
__global__ __launch_bounds__(256) void k_attn2(
    const float* __restrict__ Qg, const float* __restrict__ KV,
    float* __restrict__ PB) {
    int wid = (blockIdx.x << 2) + (threadIdx.x >> 6);
    int L = threadIdx.x & 63;
    int bh = wid / TPB;
    int rem = wid - bh * TPB;
    int s = 0;
    while (rem >= 16 - 2*s) { rem -= 16 - 2*s; ++s; }
    int t = 2*s + rem;
    int b = bh >> 3, h = bh & 7;
    int qmin = t * QW;
    int k0 = s * CH;
    int kend = min(k0 + CH, qmin + QW);
    int nkey = kend - k0;

    const float SC = 0.35355339059327373f * LOG2E;   // 1/sqrt(8) * log2(e)
    const float* qp = Qg + ((size_t)(b*Ss + qmin + L))*D + h*HD;
    float4 qa0 = *(const float4*)(qp);
    float4 qb0 = *(const float4*)(qp + 4);
    float4 qa1 = *(const float4*)(qp + 64*D);
    float4 qb1 = *(const float4*)(qp + 64*D + 4);
    qa0.x*=SC; qa0.y*=SC; qa0.z*=SC; qa0.w*=SC;
    qb0.x*=SC; qb0.y*=SC; qb0.z*=SC; qb0.w*=SC;
    qa1.x*=SC; qa1.y*=SC; qa1.z*=SC; qa1.w*=SC;
    qb1.x*=SC; qb1.y*=SC; qb1.z*=SC; qb1.w*=SC;

    float m0 = -INFINITY, m1 = -INFINITY, l0 = 0.f, l1 = 0.f;
    float o0[8] = {0,0,0,0,0,0,0,0};
    float o1[8] = {0,0,0,0,0,0,0,0};

    const float4* kvb = (const float4*)(KV + (((size_t)bh*Ss + k0) << 4));

    for (int j0 = 0; j0 < nkey; j0 += 16) {
        float s0[16], s1[16];
        #pragma unroll
        for (int jj = 0; jj < 16; ++jj) {
            const float4* kv = kvb + (size_t)(j0 + jj)*4;
            float4 ka = kv[0];
            float4 kb = kv[1];
            s0[jj] = qa0.x*ka.x + qa0.y*ka.y + qa0.z*ka.z + qa0.w*ka.w
                   + qb0.x*kb.x + qb0.y*kb.y + qb0.z*kb.z + qb0.w*kb.w;
            s1[jj] = qa1.x*ka.x + qa1.y*ka.y + qa1.z*ka.z + qa1.w*ka.w
                   + qb1.x*kb.x + qb1.y*kb.y + qb1.z*kb.z + qb1.w*kb.w;
        }
        int relbase = k0 + j0 - qmin;
        if (relbase + 15 > 0) {          // only near-diagonal blocks mask
            #pragma unroll
            for (int jj = 0; jj < 16; ++jj) {
                int rel = relbase + jj;
                if (rel > L)      s0[jj] = -1e30f;
                if (rel > L + 64) s1[jj] = -1e30f;
            }
        }
        float tm0 = s0[0], tm1 = s1[0];
        #pragma unroll
        for (int jj = 1; jj < 16; ++jj) {
            tm0 = fmaxf(tm0, s0[jj]);
            tm1 = fmaxf(tm1, s1[jj]);
        }
        if (__any((tm0 > m0) || (tm1 > m1))) {
            float mn0 = fmaxf(m0, tm0), mn1 = fmaxf(m1, tm1);
            float r0 = exp2f(m0 - mn0), r1 = exp2f(m1 - mn1);
            m0 = mn0; m1 = mn1;
            l0 *= r0; l1 *= r1;
            #pragma unroll
            for (int e = 0; e < 8; ++e) { o0[e] *= r0; o1[e] *= r1; }
        }
        #pragma unroll
        for (int jj = 0; jj < 16; ++jj) {
            const float4* kv = kvb + (size_t)(j0 + jj)*4;
            float4 va = kv[2];
            float4 vb = kv[3];
            float p0 = exp2f(s0[jj] - m0);
            float p1 = exp2f(s1[jj] - m1);
            l0 += p0; l1 += p1;
            o0[0] += p0*va.x; o0[1] += p0*va.y; o0[2] += p0*va.z; o0[3] += p0*va.w;
            o0[4] += p0*vb.x; o0[5] += p0*vb.y; o0[6] += p0*vb.z; o0[7] += p0*vb.w;
            o1[0] += p1*va.x; o1[1] += p1*va.y; o1[2] += p1*va.z; o1[3] += p1*va.w;
            o1[4] += p1*vb.x; o1[5] += p1*vb.y; o1[6] += p1*vb.z; o1[7] += p1*vb.w;
        }
    }
    float* pb = PB + (size_t)wid * 1280;
    pb[L]        = m0; pb[64 + L]        = m1;
    pb[128 + L]  = l0; pb[128 + 64 + L]  = l1;
    #pragma unroll
    for (int e = 0; e < 8; ++e) {
        pb[(2+e)*128 + L]      = o0[e];
        pb[(2+e)*128 + 64 + L] = o1[e];
    }
}

// ---------------- combine partials -> O (exp2 domain) ----------------
__global__ __launch_bounds__(128) void k_comb(const float* __restrict__ PB,
                                              float* __restrict__ Og) {
    int qs = threadIdx.x;           // 0..127
    int t  = blockIdx.x & 15;
    int bh = blockIdx.x >> 4;
    int b = bh >> 3, h = bh & 7;
    int nc = (t >> 1) + 1;
    float M = -INFINITY, Lx = 0.f;
    float O[8] = {0,0,0,0,0,0,0,0};
    for (int s3 = 0; s3 < nc; ++s3) {
        int idx = s3*(17 - s3) + (t - 2*s3);
        const float* pb = PB + (size_t)(bh*TPB + idx) * 1280;
        float m = pb[qs];
        float l = pb[128 + qs];
        float nm = fmaxf(M, m);
        float a = exp2f(M - nm), c = exp2f(m - nm);
        Lx = Lx*a + l*c;
        #pragma unroll
        for (int e = 0; e < 8; ++e) O[e] = O[e]*a + pb[(2+e)*128 + qs]*c;
        M = nm;
    }
    float inv = 1.0f / Lx;
    float* op = Og + ((size_t)(b*Ss + t*QW + qs))*D + h*HD;
    #pragma unroll
    for (int e = 0; e < 8; ++e) op[e] = O[e] * inv;
}

// ---------------- x += O @ Wo (readlane bcast, no syncs in loop) ----------
__global__ __launch_bounds__(256) void k_post1(
    float* __restrict__ X, const float* __restrict__ Og,
    const float* __restrict__ Wo) {
    __shared__ float ws_[D*D];
    int tid = threadIdx.x;
    for (int i = tid; i < D*D; i += 256) ws_[i] = Wo[i];
    __syncthreads();
    int w = tid >> 6, d = tid & 63;
    int t0 = blockIdx.x * 32;
    for (int it = 0; it < 8; ++it) {
        int t = t0 + it*4 + w;
        float ov = Og[t*D + d];
        float a = 0.f;
        #pragma unroll
        for (int j = 0; j < D; ++j) a += rdlane(ov, j) * ws_[j*D + d];
        X[t*D + d] += a;
    }
}

// ---------------- rms2 + W1 + gelu -> U (transposed LDS tile) -------------
__global__ __launch_bounds__(256) void k_ffn1(
    const float* __restrict__ X, const float* __restrict__ g2,
    const float* __restrict__ W1, float* __restrict__ U) {
    __shared__ __align__(16) float h2t[64][20];   // [dim][token], 80B rows
    __shared__ float part[16][16];
    __shared__ float g_s[D];
    int tid = threadIdx.x;
    if (tid < D) g_s[tid] = g2[tid];
    int t0 = blockIdx.x * 16;
    int tk = tid >> 4, li = tid & 15;
    float x0 = X[(t0+tk)*D + li];
    float x1 = X[(t0+tk)*D + li + 16];
    float x2 = X[(t0+tk)*D + li + 32];
    float x3 = X[(t0+tk)*D + li + 48];
    part[tk][li] = x0*x0 + x1*x1 + x2*x2 + x3*x3;
    __syncthreads();
    if (tid < 16) {
        float s = 0.f;
        #pragma unroll
        for (int i = 0; i < 16; ++i) s += part[tid][i];
        part[tid][0] = 1.0f / sqrtf(s * (1.0f/D) + 1e-6f);
    }
    __syncthreads();
    float r = part[tk][0];
    h2t[li][tk]      = x0 * g_s[li]      * r;
    h2t[li + 16][tk] = x1 * g_s[li + 16] * r;
    h2t[li + 32][tk] = x2 * g_s[li + 32] * r;
    h2t[li + 48][tk] = x3 * g_s[li + 48] * r;
    __syncthreads();
    int f = tid;
    float acc[16];
    #pragma unroll
    for (int i = 0; i < 16; ++i) acc[i] = 0.f;
    for (int j = 0; j < D; ++j) {
        float wv = W1[j*FFNx + f];
        const float4* hp = (const float4*)&h2t[j][0];
        float4 a0 = hp[0], a1 = hp[1], a2 = hp[2], a3 = hp[3];
        acc[0] += a0.x*wv;  acc[1] += a0.y*wv;  acc[2] += a0.z*wv;  acc[3] += a0.w*wv;
        acc[4] += a1.x*wv;  acc[5] += a1.y*wv;  acc[6] += a1.z*wv;  acc[7] += a1.w*wv;
        acc[8] += a2.x*wv;  acc[9] += a2.y*wv;  acc[10]+= a2.z*wv;  acc[11]+= a2.w*wv;
        acc[12]+= a3.x*wv;  acc[13]+= a3.y*wv;  acc[14]+= a3.z*wv;  acc[15]+= a3.w*wv;
    }
    #pragma unroll
    for (int i = 0; i < 16; ++i) {
        float u = acc[i];
        u = 0.5f * u * (1.0f + erff(u * 0.70710678118654752f));
        U[(t0 + i)*FFNx + f] = u;
    }
}

// ---------------- x += U @ W2 (transposed LDS tile) ----------------
__global__ __launch_bounds__(256) void k_ffn2(
    float* __restrict__ X, const float* __restrict__ U,
    const float* __restrict__ W2) {
    __shared__ __align__(16) float ult[FFNx][20];  // [f][token]
    __shared__ float red[4][16][D];
    int tid = threadIdx.x;
    int t0 = blockIdx.x * 16;
    #pragma unroll
    for (int k = 0; k < 16; ++k) ult[tid][k] = U[(t0 + k)*FFNx + tid];
    __syncthreads();
    int d = tid & 63, fp = tid >> 6;
    float acc[16];
    #pragma unroll
    for (int i = 0; i < 16; ++i) acc[i] = 0.f;
    for (int fo = 0; fo < 64; ++fo) {
        int f = fp*64 + fo;
        float wv = W2[f*D + d];
        const float4* up = (const float4*)&ult[f][0];
        float4 u0 = up[0], u1 = up[1], u2 = up[2], u3 = up[3];
        acc[0] += u0.x*wv;  acc[1] += u0.y*wv;  acc[2] += u0.z*wv;  acc[3] += u0.w*wv;
        acc[4] += u1.x*wv;  acc[5] += u1.y*wv;  acc[6] += u1.z*wv;  acc[7] += u1.w*wv;
        acc[8] += u2.x*wv;  acc[9] += u2.y*wv;  acc[10]+= u2.z*wv;  acc[11]+= u2.w*wv;
        acc[12]+= u3.x*wv;  acc[13]+= u3.y*wv;  acc[14]+= u3.z*wv;  acc[15]+= u3.w*wv;
    }
    #pragma unroll
    for (int i = 0; i < 16; ++i) red[fp][i][d] = acc[i];
    __syncthreads();
    int tk = tid >> 6;
    #pragma unroll
    for (int k = 0; k < 4; ++k) {
        int tt = tk + k*4;
        float sum = red[0][tt][d] + red[1][tt][d] + red[2][tt][d] + red[3][tt][d];
        X[(t0 + tt)*D + d] += sum;
    }
}

// ---------------- head ----------------
__global__ __launch_bounds__(256) void k_head(
    const float* __restrict__ X, const float* __restrict__ Wh,
    const float* __restrict__ bh, float* __restrict__ logit1,
    int* __restrict__ em) {
    int tid = threadIdx.x;
    int w = tid >> 6, d = tid & 63;
    int t = blockIdx.x*4 + w;
    float xv = X[t*D + d];
    float p0 = xv * Wh[d*2];
    float p1 = xv * Wh[d*2 + 1];
    #pragma unroll
    for (int off = 32; off; off >>= 1) {
        p0 += __shfl_xor(p0, off);
        p1 += __shfl_xor(p1, off);
    }
    if (d == 0) {
        float l0 = p0 + bh[0], l1 = p1 + bh[1];
        em[t] = (l0 > l1) ? 1 : 0;
        logit1[t] = l1;
    }
}

// ---------------- reg term ----------------
__global__ void k_reg(const float* __restrict__ logit1, float* __restrict__ outreg) {
    __shared__ float red[256];
    int tid = threadIdx.x;
    float s = 0.f;
    for (int i = tid; i < NT; i += 256) s += logit1[i];
    red[tid] = s;
    __syncthreads();
    for (int off = 128; off; off >>= 1) {
        if (tid < off) red[tid] += red[tid + off];
        __syncthreads();
    }
    if (tid == 0) *outreg = red[0] * (1.0f / NT);
}

// ---------------- per-batch scan ----------------
__global__ __launch_bounds__(256) void k_scan(const int* __restrict__ em,
                                              int* __restrict__ cp) {
    __shared__ int ssum[256], smax[256];
    __shared__ int sany, stot;
    int b = blockIdx.x, tid = threadIdx.x;
    const int* e = em + b*Ss;
    int base = tid * 8;
    int loc[8];
    int lsum = 0, lor = 0;
    #pragma unroll
    for (int i = 0; i < 8; ++i) { loc[i] = e[base + i]; lsum += loc[i]; lor |= loc[i]; }
    ssum[tid] = lor;
    __syncthreads();
    if (tid == 0) { int a = 0; for (int i = 0; i < 256; ++i) a |= ssum[i]; sany = a; }
    __syncthreads();
    int any = sany;
    __syncthreads();
    if (!any && tid == 255) { loc[7] = 1; lsum = 1; }
    int prev = (tid == 0) ? 1 : e[base - 1];
    if (!any && tid) prev = 0;
    int mk[8];
    int lmax = -1;
    #pragma unroll
    for (int i = 0; i < 8; ++i) {
        int pe = (i == 0) ? prev : loc[i - 1];
        if (i == 7 && !any && tid == 255) pe = e[base + 6];
        mk[i] = pe ? (base + i) : -1;
        lmax = max(lmax, mk[i]);
    }
    ssum[tid] = lsum; smax[tid] = lmax;
    __syncthreads();
    if (tid == 0) {
        int rs = 0, rm = -1;
        for (int i = 0; i < 256; ++i) {
            int ts = ssum[i], tm = smax[i];
            ssum[i] = rs; smax[i] = rm;
            rs += ts; rm = max(rm, tm);
        }
        stot = rs;
    }
    __syncthreads();
    int run = ssum[tid], rmax = smax[tid], tot = stot;
    int* cpb = cp + b*Ss;
    #pragma unroll
    for (int i = 0; i < 8; ++i) {
        int s = base + i;
        rmax = max(rmax, mk[i]);
        int chunk = run;
        run += loc[i];
        int pos = s - rmax;
        bool valid = (chunk < tot) && (chunk < MAXC) && (pos < MCL);
        cpb[s] = valid ? (chunk * MCL + pos) : -1;
    }
}

// ---------------- fill / scatter ----------------
__global__ void k_fill(float* __restrict__ out, const float* __restrict__ pad,
                       const int* __restrict__ padid) {
    int i = blockIdx.x * blockDim.x + threadIdx.x;
    constexpr int N4  = Bb * MAXC * MCL * D / 4;
    constexpr int NI4 = Bb * MAXC * MCL / 4;
    if (i < N4) {
        ((float4*)out)[i] = ((const float4*)pad)[i & 15];
    } else if (i < N4 + NI4) {
        float pv = (float)(*padid);
        float4 v; v.x = pv; v.y = pv; v.z = pv; v.w = pv;
        ((float4*)out)[i] = v;
    }
}

__global__ __launch_bounds__(256) void k_scatter(
    const float* __restrict__ X, const int* __restrict__ cp,
    const int* __restrict__ ids, float* __restrict__ out) {
    int tid = threadIdx.x;
    int w = tid >> 6, d = tid & 63;
    int t = blockIdx.x*4 + w;
    int c = cp[t];
    if (c < 0) return;
    int b = t >> 11;
    float* dst = out + ((size_t)(b * MAXC * MCL) + c) * D;
    dst[d] = X[t*D + d];
    if (d == 0)
        out[(size_t)Bb*MAXC*MCL*D + (size_t)b*MAXC*MCL + c] = (float)ids[t];
}

// ---------------- launch ----------------
extern "C" void kernel_launch(void* const* d_in, const int* in_sizes, int n_in,
                              void* d_out, int out_size, void* d_ws, size_t ws_size,
                              hipStream_t stream) {
    const float* x    = (const float*)d_in[0];
    const float* pad  = (const float*)d_in[1];
    const int*   xids = (const int*)  d_in[2];
    const int*   padid= (const int*)  d_in[3];
    const float* Wq   = (const float*)d_in[4];
    const float* Wk   = (const float*)d_in[5];
    const float* Wv   = (const float*)d_in[6];
    const float* Wo   = (const float*)d_in[7];
    const float* ln1  = (const float*)d_in[8];
    const float* ln2  = (const float*)d_in[9];
    const float* W1   = (const float*)d_in[10];
    const float* W2   = (const float*)d_in[11];
    const float* Wh   = (const float*)d_in[12];
    const float* bh   = (const float*)d_in[13];
    float* out = (float*)d_out;
    float* ws  = (float*)d_ws;

    float* X  = ws + WX;
    float* Qb = ws + WQ;
    float* KVb= ws + WKV;
    float* Ob = ws + WO;
    float* PBb= ws + WPB;
    float* Ub = ws + WU;
    float* L1b= ws + WL1;
    int*   EMb= (int*)(ws + WEM);
    int*   CPb= (int*)(ws + WCP);
    float* ct = ws + WCT;
    float* st = ws + WST;

    k_init<<<2048, 256, 0, stream>>>(x, X, ct, st);
    for (int l = 0; l < NL; ++l) {
        k_qkv <<<256, 256, 0, stream>>>(X, Wq + l*D*D, Wk + l*D*D, Wv + l*D*D,
                                        ln1 + l*D, ct, st, Qb, KVb);
        k_attn2<<<NTASK/4, 256, 0, stream>>>(Qb, KVb, PBb);
        k_comb <<<32*16, 128, 0, stream>>>(PBb, Ob);
        k_post1<<<256, 256, 0, stream>>>(X, Ob, Wo + l*D*D);
        k_ffn1<<<NT/16, 256, 0, stream>>>(X, ln2 + l*D, W1 + l*D*FFNx, Ub);
        k_ffn2<<<NT/16, 256, 0, stream>>>(X, Ub, W2 + l*FFNx*D);
    }
    k_head<<<NT/4, 256, 0, stream>>>(X, Wh, bh, L1b, EMb);
    k_reg <<<1, 256, 0, stream>>>(L1b, out + (size_t)Bb*MAXC*MCL*D + Bb*MAXC*MCL);
    k_scan<<<Bb, 256, 0, stream>>>(EMb, CPb);
    k_fill<<<(Bb*MAXC*MCL*D/4 + Bb*MAXC*MCL/4 + 255)/256, 256, 0, stream>>>(out, pad, padid);
    k_scatter<<<NT/4, 256, 0, stream>>>(X, CPb, xids, out);
}

// Round 4
// 446.077 us; speedup vs baseline: 1.7025x; 1.0918x over previous
//
#include <hip/hip_runtime.h>
#include <math.h>

// ---------------- problem constants (fixed by setup_inputs) ----------------
constexpr int D   = 64;
constexpr int H   = 8;
constexpr int HD  = 8;
constexpr int NL  = 3;
constexpr int FFNx= 256;
constexpr int Bb  = 4;
constexpr int Ss  = 2048;
constexpr int NT  = Bb * Ss;        // 8192 tokens
constexpr int MAXC= 1024;
constexpr int MCL = 16;

// attention task decomposition: uniform tasks, chunk-major enumeration
constexpr int QW   = 128;            // queries per wave (2 per lane)
constexpr int CH   = 128;            // keys per chunk task (== QW -> uniform)
constexpr int TPB  = 136;            // tasks per (b,h): sum_{s=0..15} (16-s)
constexpr int NTASK= 32 * TPB;       // 4352 waves

// ---------------- workspace layout (float elements) ----------------
constexpr size_t WX  = 0;                        // [NT*D] = 524288
constexpr size_t WQ  = 524288;                   // [NT*D] (U alias, needs NT*FFN)
constexpr size_t WKV = 2621440;                  // [32*2048*16] interleaved K|V
constexpr size_t WO  = 3670016;                  // [NT*D]
constexpr size_t WPB = 4194304;                  // [NTASK*1280] attn partials
constexpr size_t WU  = WQ;                       // [NT*FFN] aliases Q
constexpr size_t WL1 = 9764864;                  // [NT]
constexpr size_t WEM = WL1 + NT;                 // [NT] int
constexpr size_t WCP = WEM + NT;                 // [NT] int
constexpr size_t WCT = WCP + NT;                 // [Ss*4]
constexpr size_t WST = WCT + Ss*4;               // [Ss*4]  (end ~9.81M floats)

constexpr float LOG2E = 1.4426950408889634f;

__device__ __forceinline__ float rdlane(float v, int l) {
    return __builtin_bit_cast(float, __builtin_amdgcn_readlane(__builtin_bit_cast(int, v), l));
}

// ---------------- init: copy x -> X, build rope tables ----------------
__global__ void k_init(const float* __restrict__ x, float* __restrict__ X,
                       float* __restrict__ ct, float* __restrict__ st) {
    int i = blockIdx.x * blockDim.x + threadIdx.x;
    constexpr int N4 = NT * D / 4;
    if (i < N4) ((float4*)X)[i] = ((const float4*)x)[i];
    if (i < Ss * 4) {
        int s = i >> 2, f = i & 3;
        const float fr[4] = {1.0f, 0.1f, 0.01f, 0.001f};
        float ang = (float)s * fr[f];
        ct[i] = cosf(ang);
        st[i] = sinf(ang);
    }
}

// ---------------- rmsnorm + QKV + rope (wave-per-token, readlane bcast) ----
// Q -> [b,s,h*8+e]; K,V -> interleaved KV[bh][s][0..7=K, 8..15=V]
__global__ __launch_bounds__(256) void k_qkv(
    const float* __restrict__ X, const float* __restrict__ Wq,
    const float* __restrict__ Wk, const float* __restrict__ Wv,
    const float* __restrict__ g1, const float* __restrict__ ct,
    const float* __restrict__ st, float* __restrict__ Q,
    float* __restrict__ KV) {
    __shared__ float wq_s[D*D], wk_s[D*D], wv_s[D*D];
    __shared__ float g_s[D];
    int tid = threadIdx.x;
    for (int i = tid; i < D*D; i += 256) {
        wq_s[i] = Wq[i]; wk_s[i] = Wk[i]; wv_s[i] = Wv[i];
    }
    if (tid < D) g_s[tid] = g1[tid];
    __syncthreads();
    int w = tid >> 6, d = tid & 63;
    int t0 = blockIdx.x * 32;
    for (int it = 0; it < 8; ++it) {
        int t = t0 + it*4 + w;
        float xv = X[t*D + d];
        float ss = xv * xv;
        #pragma unroll
        for (int off = 32; off; off >>= 1) ss += __shfl_xor(ss, off);
        float r = 1.0f / sqrtf(ss * (1.0f/D) + 1e-6f);
        float h = xv * g_s[d] * r;
        float aq = 0.f, ak = 0.f, av = 0.f;
        #pragma unroll
        for (int j = 0; j < D; ++j) {
            float hj = rdlane(h, j);
            aq += hj * wq_s[j*D + d];
            ak += hj * wk_s[j*D + d];
            av += hj * wv_s[j*D + d];
        }
        int s  = t & (Ss - 1);
        int e  = d & 7;
        int fi = e & 3;
        float c  = ct[s*4 + fi];
        float sn = st[s*4 + fi];
        float pq = __shfl_xor(aq, 4);
        float pk = __shfl_xor(ak, 4);
        float rq, rk;
        if (e < 4) { rq = aq*c - pq*sn; rk = ak*c - pk*sn; }
        else       { rq = pq*sn + aq*c; rk = pk*sn + ak*c; }
        Q[t*D + d] = rq;
        int bq = t >> 11;
        int hh = d >> 3;
        float* kvp = KV + ((((size_t)(bq*H + hh))*Ss + s) << 4);
        kvp[e]     = rk;
        kvp[8 + e] = av;
    }
}

// ---------------- causal attention, uniform split-K, exp2 domain ----------
// enumeration: s outer (off(s)=16s - s(s-1)/2), t = s..15 inner.
__global__ __launch_bounds__(256) void k_attn2(
    const float* __restrict__ Qg, const float* __restrict__ KV,
    float* __restrict__ PB) {
    int wid = (blockIdx.x << 2) + (threadIdx.x >> 6);
    int L = threadIdx.x & 63;
    int bh = wid / TPB;
    int rem = wid - bh * TPB;
    int s = 0;
    while (rem >= 16 - s) { rem -= 16 - s; ++s; }
    int t = s + rem;
    int b = bh >> 3, h = bh & 7;
    int qmin = t * QW;
    int k0 = s * CH;

    const float SC = 0.35355339059327373f * LOG2E;   // 1/sqrt(8) * log2(e)
    const float* qp = Qg + ((size_t)(b*Ss + qmin + L))*D + h*HD;
    float4 qa0 = *(const float4*)(qp);
    float4 qb0 = *(const float4*)(qp + 4);
    float4 qa1 = *(const float4*)(qp + 64*D);
    float4 qb1 = *(const float4*)(qp + 64*D + 4);
    qa0.x*=SC; qa0.y*=SC; qa0.z*=SC; qa0.w*=SC;
    qb0.x*=SC; qb0.y*=SC; qb0.z*=SC; qb0.w*=SC;
    qa1.x*=SC; qa1.y*=SC; qa1.z*=SC; qa1.w*=SC;
    qb1.x*=SC; qb1.y*=SC; qb1.z*=SC; qb1.w*=SC;

    float m0 = -INFINITY, m1 = -INFINITY, l0 = 0.f, l1 = 0.f;
    float o0[8] = {0,0,0,0,0,0,0,0};
    float o1[8] = {0,0,0,0,0,0,0,0};

    const float4* kvb = (const float4*)(KV + (((size_t)bh*Ss + k0) << 4));
    bool diag = (s == t);

    for (int j0 = 0; j0 < CH; j0 += 16) {
        float s0[16], s1[16];
        #pragma unroll
        for (int jj = 0; jj < 16; ++jj) {
            const float4* kv = kvb + (size_t)(j0 + jj)*4;
            float4 ka = kv[0];
            float4 kb = kv[1];
            s0[jj] = qa0.x*ka.x + qa0.y*ka.y + qa0.z*ka.z + qa0.w*ka.w
                   + qb0.x*kb.x + qb0.y*kb.y + qb0.z*kb.z + qb0.w*kb.w;
            s1[jj] = qa1.x*ka.x + qa1.y*ka.y + qa1.z*ka.z + qa1.w*ka.w
                   + qb1.x*kb.x + qb1.y*kb.y + qb1.z*kb.z + qb1.w*kb.w;
        }
        if (diag) {                       // wave-uniform: only diagonal chunk
            #pragma unroll
            for (int jj = 0; jj < 16; ++jj) {
                int rel = j0 + jj;
                if (rel > L)      s0[jj] = -1e30f;
                if (rel > L + 64) s1[jj] = -1e30f;
            }
        }
        float tm0 = s0[0], tm1 = s1[0];
        #pragma unroll
        for (int jj = 1; jj < 16; ++jj) {
            tm0 = fmaxf(tm0, s0[jj]);
            tm1 = fmaxf(tm1, s1[jj]);
        }
        if (__any((tm0 > m0) || (tm1 > m1))) {
            float mn0 = fmaxf(m0, tm0), mn1 = fmaxf(m1, tm1);
            float r0 = exp2f(m0 - mn0), r1 = exp2f(m1 - mn1);
            m0 = mn0; m1 = mn1;
            l0 *= r0; l1 *= r1;
            #pragma unroll
            for (int e = 0; e < 8; ++e) { o0[e] *= r0; o1[e] *= r1; }
        }
        #pragma unroll
        for (int jj = 0; jj < 16; ++jj) {
            const float4* kv = kvb + (size_t)(j0 + jj)*4;
            float4 va = kv[2];
            float4 vb = kv[3];
            float p0 = exp2f(s0[jj] - m0);
            float p1 = exp2f(s1[jj] - m1);
            l0 += p0; l1 += p1;
            o0[0] += p0*va.x; o0[1] += p0*va.y; o0[2] += p0*va.z; o0[3] += p0*va.w;
            o0[4] += p0*vb.x; o0[5] += p0*vb.y; o0[6] += p0*vb.z; o0[7] += p0*vb.w;
            o1[0] += p1*va.x; o1[1] += p1*va.y; o1[2] += p1*va.z; o1[3] += p1*va.w;
            o1[4] += p1*vb.x; o1[5] += p1*vb.y; o1[6] += p1*vb.z; o1[7] += p1*vb.w;
        }
    }
    float* pb = PB + (size_t)wid * 1280;
    pb[L]        = m0; pb[64 + L]        = m1;
    pb[128 + L]  = l0; pb[128 + 64 + L]  = l1;
    #pragma unroll
    for (int e = 0; e < 8; ++e) {
        pb[(2+e)*128 + L]      = o0[e];
        pb[(2+e)*128 + 64 + L] = o1[e];
    }
}

// ---------------- combine partials -> O (exp2 domain) ----------------
__global__ __launch_bounds__(128) void k_comb(const float* __restrict__ PB,
                                              float* __restrict__ Og) {
    int qs = threadIdx.x;           // 0..127
    int t  = blockIdx.x & 15;
    int bh = blockIdx.x >> 4;
    int b = bh >> 3, h = bh & 7;
    float M = -INFINITY, Lx = 0.f;
    float O[8] = {0,0,0,0,0,0,0,0};
    for (int s3 = 0; s3 <= t; ++s3) {
        int idx = 16*s3 - (s3*(s3-1))/2 + (t - s3);
        const float* pb = PB + (size_t)(bh*TPB + idx) * 1280;
        float m = pb[qs];
        float l = pb[128 + qs];
        float nm = fmaxf(M, m);
        float a = exp2f(M - nm), c = exp2f(m - nm);
        Lx = Lx*a + l*c;
        #pragma unroll
        for (int e = 0; e < 8; ++e) O[e] = O[e]*a + pb[(2+e)*128 + qs]*c;
        M = nm;
    }
    float inv = 1.0f / Lx;
    float* op = Og + ((size_t)(b*Ss + t*QW + qs))*D + h*HD;
    #pragma unroll
    for (int e = 0; e < 8; ++e) op[e] = O[e] * inv;
}

// ---------------- x += O @ Wo (readlane bcast) ----------------
__global__ __launch_bounds__(256) void k_post1(
    float* __restrict__ X, const float* __restrict__ Og,
    const float* __restrict__ Wo) {
    __shared__ float ws_[D*D];
    int tid = threadIdx.x;
    for (int i = tid; i < D*D; i += 256) ws_[i] = Wo[i];
    __syncthreads();
    int w = tid >> 6, d = tid & 63;
    int t0 = blockIdx.x * 32;
    for (int it = 0; it < 8; ++it) {
        int t = t0 + it*4 + w;
        float ov = Og[t*D + d];
        float a = 0.f;
        #pragma unroll
        for (int j = 0; j < D; ++j) a += rdlane(ov, j) * ws_[j*D + d];
        X[t*D + d] += a;
    }
}

// ---------------- rms2 + W1 + gelu -> U (transposed LDS tile) -------------
__global__ __launch_bounds__(256) void k_ffn1(
    const float* __restrict__ X, const float* __restrict__ g2,
    const float* __restrict__ W1, float* __restrict__ U) {
    __shared__ __align__(16) float h2t[64][20];   // [dim][token], 80B rows
    __shared__ float part[16][16];
    __shared__ float g_s[D];
    int tid = threadIdx.x;
    if (tid < D) g_s[tid] = g2[tid];
    int t0 = blockIdx.x * 16;
    int tk = tid >> 4, li = tid & 15;
    float x0 = X[(t0+tk)*D + li];
    float x1 = X[(t0+tk)*D + li + 16];
    float x2 = X[(t0+tk)*D + li + 32];
    float x3 = X[(t0+tk)*D + li + 48];
    part[tk][li] = x0*x0 + x1*x1 + x2*x2 + x3*x3;
    __syncthreads();
    if (tid < 16) {
        float s = 0.f;
        #pragma unroll
        for (int i = 0; i < 16; ++i) s += part[tid][i];
        part[tid][0] = 1.0f / sqrtf(s * (1.0f/D) + 1e-6f);
    }
    __syncthreads();
    float r = part[tk][0];
    h2t[li][tk]      = x0 * g_s[li]      * r;
    h2t[li + 16][tk] = x1 * g_s[li + 16] * r;
    h2t[li + 32][tk] = x2 * g_s[li + 32] * r;
    h2t[li + 48][tk] = x3 * g_s[li + 48] * r;
    __syncthreads();
    int f = tid;
    float acc[16];
    #pragma unroll
    for (int i = 0; i < 16; ++i) acc[i] = 0.f;
    for (int j = 0; j < D; ++j) {
        float wv = W1[j*FFNx + f];
        const float4* hp = (const float4*)&h2t[j][0];
        float4 a0 = hp[0], a1 = hp[1], a2 = hp[2], a3 = hp[3];
        acc[0] += a0.x*wv;  acc[1] += a0.y*wv;  acc[2] += a0.z*wv;  acc[3] += a0.w*wv;
        acc[4] += a1.x*wv;  acc[5] += a1.y*wv;  acc[6] += a1.z*wv;  acc[7] += a1.w*wv;
        acc[8] += a2.x*wv;  acc[9] += a2.y*wv;  acc[10]+= a2.z*wv;  acc[11]+= a2.w*wv;
        acc[12]+= a3.x*wv;  acc[13]+= a3.y*wv;  acc[14]+= a3.z*wv;  acc[15]+= a3.w*wv;
    }
    #pragma unroll
    for (int i = 0; i < 16; ++i) {
        float u = acc[i];
        u = 0.5f * u * (1.0f + erff(u * 0.70710678118654752f));
        U[(t0 + i)*FFNx + f] = u;
    }
}

// ---------------- x += U @ W2 (transposed LDS tile) ----------------
__global__ __launch_bounds__(256) void k_ffn2(
    float* __restrict__ X, const float* __restrict__ U,
    const float* __restrict__ W2) {
    __shared__ __align__(16) float ult[FFNx][20];  // [f][token]
    __shared__ float red[4][16][D];
    int tid = threadIdx.x;
    int t0 = blockIdx.x * 16;
    #pragma unroll
    for (int k = 0; k < 16; ++k) ult[tid][k] = U[(t0 + k)*FFNx + tid];
    __syncthreads();
    int d = tid & 63, fp = tid >> 6;
    float acc[16];
    #pragma unroll
    for (int i = 0; i < 16; ++i) acc[i] = 0.f;
    for (int fo = 0; fo < 64; ++fo) {
        int f = fp*64 + fo;
        float wv = W2[f*D + d];
        const float4* up = (const float4*)&ult[f][0];
        float4 u0 = up[0], u1 = up[1], u2 = up[2], u3 = up[3];
        acc[0] += u0.x*wv;  acc[1] += u0.y*wv;  acc[2] += u0.z*wv;  acc[3] += u0.w*wv;
        acc[4] += u1.x*wv;  acc[5] += u1.y*wv;  acc[6] += u1.z*wv;  acc[7] += u1.w*wv;
        acc[8] += u2.x*wv;  acc[9] += u2.y*wv;  acc[10]+= u2.z*wv;  acc[11]+= u2.w*wv;
        acc[12]+= u3.x*wv;  acc[13]+= u3.y*wv;  acc[14]+= u3.z*wv;  acc[15]+= u3.w*wv;
    }
    #pragma unroll
    for (int i = 0; i < 16; ++i) red[fp][i][d] = acc[i];
    __syncthreads();
    int tk = tid >> 6;
    #pragma unroll
    for (int k = 0; k < 4; ++k) {
        int tt = tk + k*4;
        float sum = red[0][tt][d] + red[1][tt][d] + red[2][tt][d] + red[3][tt][d];
        X[(t0 + tt)*D + d] += sum;
    }
}

// ---------------- head ----------------
__global__ __launch_bounds__(256) void k_head(
    const float* __restrict__ X, const float* __restrict__ Wh,
    const float* __restrict__ bh, float* __restrict__ logit1,
    int* __restrict__ em) {
    int tid = threadIdx.x;
    int w = tid >> 6, d = tid & 63;
    int t = blockIdx.x*4 + w;
    float xv = X[t*D + d];
    float p0 = xv * Wh[d*2];
    float p1 = xv * Wh[d*2 + 1];
    #pragma unroll
    for (int off = 32; off; off >>= 1) {
        p0 += __shfl_xor(p0, off);
        p1 += __shfl_xor(p1, off);
    }
    if (d == 0) {
        float l0 = p0 + bh[0], l1 = p1 + bh[1];
        em[t] = (l0 > l1) ? 1 : 0;
        logit1[t] = l1;
    }
}

// ---------------- reg term ----------------
__global__ void k_reg(const float* __restrict__ logit1, float* __restrict__ outreg) {
    __shared__ float red[256];
    int tid = threadIdx.x;
    float s = 0.f;
    for (int i = tid; i < NT; i += 256) s += logit1[i];
    red[tid] = s;
    __syncthreads();
    for (int off = 128; off; off >>= 1) {
        if (tid < off) red[tid] += red[tid + off];
        __syncthreads();
    }
    if (tid == 0) *outreg = red[0] * (1.0f / NT);
}

// ---------------- per-batch scan ----------------
__global__ __launch_bounds__(256) void k_scan(const int* __restrict__ em,
                                              int* __restrict__ cp) {
    __shared__ int ssum[256], smax[256];
    __shared__ int sany, stot;
    int b = blockIdx.x, tid = threadIdx.x;
    const int* e = em + b*Ss;
    int base = tid * 8;
    int loc[8];
    int lsum = 0, lor = 0;
    #pragma unroll
    for (int i = 0; i < 8; ++i) { loc[i] = e[base + i]; lsum += loc[i]; lor |= loc[i]; }
    ssum[tid] = lor;
    __syncthreads();
    if (tid == 0) { int a = 0; for (int i = 0; i < 256; ++i) a |= ssum[i]; sany = a; }
    __syncthreads();
    int any = sany;
    __syncthreads();
    if (!any && tid == 255) { loc[7] = 1; lsum = 1; }
    int prev = (tid == 0) ? 1 : e[base - 1];
    if (!any && tid) prev = 0;
    int mk[8];
    int lmax = -1;
    #pragma unroll
    for (int i = 0; i < 8; ++i) {
        int pe = (i == 0) ? prev : loc[i - 1];
        if (i == 7 && !any && tid == 255) pe = e[base + 6];
        mk[i] = pe ? (base + i) : -1;
        lmax = max(lmax, mk[i]);
    }
    ssum[tid] = lsum; smax[tid] = lmax;
    __syncthreads();
    if (tid == 0) {
        int rs = 0, rm = -1;
        for (int i = 0; i < 256; ++i) {
            int ts = ssum[i], tm = smax[i];
            ssum[i] = rs; smax[i] = rm;
            rs += ts; rm = max(rm, tm);
        }
        stot = rs;
    }
    __syncthreads();
    int run = ssum[tid], rmax = smax[tid], tot = stot;
    int* cpb = cp + b*Ss;
    #pragma unroll
    for (int i = 0; i < 8; ++i) {
        int s = base + i;
        rmax = max(rmax, mk[i]);
        int chunk = run;
        run += loc[i];
        int pos = s - rmax;
        bool valid = (chunk < tot) && (chunk < MAXC) && (pos < MCL);
        cpb[s] = valid ? (chunk * MCL + pos) : -1;
    }
}

// ---------------- fill / scatter ----------------
__global__ void k_fill(float* __restrict__ out, const float* __restrict__ pad,
                       const int* __restrict__ padid) {
    int i = blockIdx.x * blockDim.x + threadIdx.x;
    constexpr int N4  = Bb * MAXC * MCL * D / 4;
    constexpr int NI4 = Bb * MAXC * MCL / 4;
    if (i < N4) {
        ((float4*)out)[i] = ((const float4*)pad)[i & 15];
    } else if (i < N4 + NI4) {
        float pv = (float)(*padid);
        float4 v; v.x = pv; v.y = pv; v.z = pv; v.w = pv;
        ((float4*)out)[i] = v;
    }
}

__global__ __launch_bounds__(256) void k_scatter(
    const float* __restrict__ X, const int* __restrict__ cp,
    const int* __restrict__ ids, float* __restrict__ out) {
    int tid = threadIdx.x;
    int w = tid >> 6, d = tid & 63;
    int t = blockIdx.x*4 + w;
    int c = cp[t];
    if (c < 0) return;
    int b = t >> 11;
    float* dst = out + ((size_t)(b * MAXC * MCL) + c) * D;
    dst[d] = X[t*D + d];
    if (d == 0)
        out[(size_t)Bb*MAXC*MCL*D + (size_t)b*MAXC*MCL + c] = (float)ids[t];
}

// ---------------- launch ----------------
extern "C" void kernel_launch(void* const* d_in, const int* in_sizes, int n_in,
                              void* d_out, int out_size, void* d_ws, size_t ws_size,
                              hipStream_t stream) {
    const float* x    = (const float*)d_in[0];
    const float* pad  = (const float*)d_in[1];
    const int*   xids = (const int*)  d_in[2];
    const int*   padid= (const int*)  d_in[3];
    const float* Wq   = (const float*)d_in[4];
    const float* Wk   = (const float*)d_in[5];
    const float* Wv   = (const float*)d_in[6];
    const float* Wo   = (const float*)d_in[7];
    const float* ln1  = (const float*)d_in[8];
    const float* ln2  = (const float*)d_in[9];
    const float* W1   = (const float*)d_in[10];
    const float* W2   = (const float*)d_in[11];
    const float* Wh   = (const float*)d_in[12];
    const float* bh   = (const float*)d_in[13];
    float* out = (float*)d_out;
    float* ws  = (float*)d_ws;

    float* X  = ws + WX;
    float* Qb = ws + WQ;
    float* KVb= ws + WKV;
    float* Ob = ws + WO;
    float* PBb= ws + WPB;
    float* Ub = ws + WU;
    float* L1b= ws + WL1;
    int*   EMb= (int*)(ws + WEM);
    int*   CPb= (int*)(ws + WCP);
    float* ct = ws + WCT;
    float* st = ws + WST;

    k_init<<<2048, 256, 0, stream>>>(x, X, ct, st);
    for (int l = 0; l < NL; ++l) {
        k_qkv <<<256, 256, 0, stream>>>(X, Wq + l*D*D, Wk + l*D*D, Wv + l*D*D,
                                        ln1 + l*D, ct, st, Qb, KVb);
        k_attn2<<<NTASK/4, 256, 0, stream>>>(Qb, KVb, PBb);
        k_comb <<<32*16, 128, 0, stream>>>(PBb, Ob);
        k_post1<<<256, 256, 0, stream>>>(X, Ob, Wo + l*D*D);
        k_ffn1<<<NT/16, 256, 0, stream>>>(X, ln2 + l*D, W1 + l*D*FFNx, Ub);
        k_ffn2<<<NT/16, 256, 0, stream>>>(X, Ub, W2 + l*FFNx*D);
    }
    k_head<<<NT/4, 256, 0, stream>>>(X, Wh, bh, L1b, EMb);
    k_reg <<<1, 256, 0, stream>>>(L1b, out + (size_t)Bb*MAXC*MCL*D + Bb*MAXC*MCL);
    k_scan<<<Bb, 256, 0, stream>>>(EMb, CPb);
    k_fill<<<(Bb*MAXC*MCL*D/4 + Bb*MAXC*MCL/4 + 255)/256, 256, 0, stream>>>(out, pad, padid);
    k_scatter<<<NT/4, 256, 0, stream>>>(X, CPb, xids, out);
}